// Round 1
// baseline (15832.684 us; speedup 1.0000x reference)
//
#include <hip/hip_runtime.h>
#include <math.h>

#define TPB 256

__device__ __forceinline__ float silu_f(float x) { return x / (1.f + __expf(-x)); }

// ---------------- node pre: xs = s@W1_s/8, xv = v@W1_v/sqrt(32) ----------------
__global__ __launch_bounds__(256) void k_node_pre(
    const float* __restrict__ nf, const float* __restrict__ W1s, const float* __restrict__ W1v,
    float* __restrict__ xs, float* __restrict__ xv, int n)
{
    __shared__ float s_lds[4][64];
    __shared__ float v_lds[4][96];
    int w = threadIdx.x >> 6, l = threadIdx.x & 63;
    int node = blockIdx.x * 4 + w;
    if (node < n) {
        const float* row = nf + (long)node * 160;
        s_lds[w][l] = row[l];
        v_lds[w][l] = row[64 + l];
        if (l < 32) v_lds[w][64 + l] = row[128 + l];
    }
    __syncthreads();
    if (node >= n) return;
    float a = 0.f;
    #pragma unroll 8
    for (int i = 0; i < 64; ++i) a += s_lds[w][i] * W1s[i * 64 + l];
    xs[(long)node * 64 + l] = a * 0.125f;

    int k = l >> 1, c = l & 1;
    float b = 0.f;
    #pragma unroll 8
    for (int m = 0; m < 32; ++m) b += v_lds[w][m * 3 + c] * W1v[m * 32 + k];
    xv[(long)node * 96 + k * 3 + c] = b * 0.17677669529663687f;
    if (l < 32) {
        float d = 0.f;
        #pragma unroll 8
        for (int m = 0; m < 32; ++m) d += v_lds[w][m * 3 + 2] * W1v[m * 32 + l];
        xv[(long)node * 96 + l * 3 + 2] = d * 0.17677669529663687f;
    }
}

// ---------------- edge kernel: MLP + messages + atomic scatter ----------------
__global__ __launch_bounds__(256) void k_edge(
    const float* __restrict__ edge_sh, const float* __restrict__ edge_embed,
    const float* __restrict__ fc_w1, const float* __restrict__ fc_b1,
    const float* __restrict__ fc_w2, const float* __restrict__ fc_b2,
    const int* __restrict__ ei,
    const float* __restrict__ xs, const float* __restrict__ xv,
    float* __restrict__ agg, int nE)
{
    __shared__ float w1[512];      // [b][h]
    __shared__ float b1s[64];
    __shared__ float w2t[192 * 64]; // [j][h] transposed
    __shared__ float b2s[192];
    int tid = threadIdx.x;
    for (int i = tid; i < 512; i += TPB) w1[i] = fc_w1[i];
    if (tid < 64) b1s[tid] = fc_b1[tid];
    for (int i = tid; i < 12288; i += TPB) { int h = i / 192, j = i % 192; w2t[j * 64 + h] = fc_w2[i]; }
    if (tid < 192) b2s[tid] = fc_b2[tid];
    __syncthreads();

    int e = blockIdx.x * TPB + tid;
    if (e >= nE) return;

    float ee[8];
    {
        const float4* p = (const float4*)(edge_embed + (long)e * 8);
        float4 u = p[0], v = p[1];
        ee[0] = u.x; ee[1] = u.y; ee[2] = u.z; ee[3] = u.w;
        ee[4] = v.x; ee[5] = v.y; ee[6] = v.z; ee[7] = v.w;
    }
    float hid[64];
    #pragma unroll
    for (int h = 0; h < 64; ++h) {
        float a = b1s[h];
        #pragma unroll
        for (int b = 0; b < 8; ++b) a += ee[b] * w1[b * 64 + h];
        hid[h] = a / (1.f + __expf(-a));
    }

    int src = ei[e], dst = ei[nE + e];
    float4 sh = *(const float4*)(edge_sh + (long)e * 4);
    const float qdeg = 0.25f;  // 1/sqrt(avg_deg=16), folded into sh
    float sh0 = sh.x * qdeg;
    float s1x = sh.y * qdeg, s1y = sh.z * qdeg, s1z = sh.w * qdeg;

    const float* xsrow = xs + (long)src * 64;
    const float* xvrow = xv + (long)src * 96;
    float* aggrow = agg + (long)dst * 384;

    #pragma unroll 1
    for (int j = 0; j < 64; ++j) {
        const float4* p0 = (const float4*)(w2t + j * 64);
        const float4* p1 = (const float4*)(w2t + (64 + j) * 64);
        float a0 = b2s[j], a1 = b2s[64 + j];
        #pragma unroll
        for (int q = 0; q < 16; ++q) {
            float4 u = p0[q], v = p1[q];
            a0 += hid[4 * q] * u.x + hid[4 * q + 1] * u.y + hid[4 * q + 2] * u.z + hid[4 * q + 3] * u.w;
            a1 += hid[4 * q] * v.x + hid[4 * q + 1] * v.y + hid[4 * q + 2] * v.z + hid[4 * q + 3] * v.w;
        }
        float xsj = xsrow[j];
        atomicAdd(aggrow + j, a0 * xsj * sh0);              // m0_a
        float t = a1 * xsj;                                  // m1_a
        atomicAdd(aggrow + 96 + 3 * j,     t * s1x);
        atomicAdd(aggrow + 96 + 3 * j + 1, t * s1y);
        atomicAdd(aggrow + 96 + 3 * j + 2, t * s1z);
    }
    #pragma unroll 1
    for (int k = 0; k < 32; ++k) {
        const float4* p0 = (const float4*)(w2t + (128 + k) * 64);
        const float4* p1 = (const float4*)(w2t + (160 + k) * 64);
        float a2 = b2s[128 + k], a3 = b2s[160 + k];
        #pragma unroll
        for (int q = 0; q < 16; ++q) {
            float4 u = p0[q], v = p1[q];
            a2 += hid[4 * q] * u.x + hid[4 * q + 1] * u.y + hid[4 * q + 2] * u.z + hid[4 * q + 3] * u.w;
            a3 += hid[4 * q] * v.x + hid[4 * q + 1] * v.y + hid[4 * q + 2] * v.z + hid[4 * q + 3] * v.w;
        }
        float vx = xvrow[3 * k], vy = xvrow[3 * k + 1], vz = xvrow[3 * k + 2];
        atomicAdd(aggrow + 288 + 3 * k,     a2 * vx * sh0); // m1_b
        atomicAdd(aggrow + 288 + 3 * k + 1, a2 * vy * sh0);
        atomicAdd(aggrow + 288 + 3 * k + 2, a2 * vz * sh0);
        float dotv = vx * s1x + vy * s1y + vz * s1z;
        atomicAdd(aggrow + 64 + k, a3 * dotv * 0.57735026918962576f); // m0_b
    }
}

// ---------------- node post: linear + gating + residual ----------------
__global__ __launch_bounds__(256) void k_node_post(
    const float* __restrict__ nf, const float* __restrict__ agg,
    const float* __restrict__ W2s, const float* __restrict__ W2v,
    const float* __restrict__ Wscs, const float* __restrict__ Wscv,
    float* __restrict__ out, int n)
{
    __shared__ float ag[2][384];
    __shared__ float sv[2][160];
    __shared__ float gsrc[2][32];
    int half = threadIdx.x >> 7;
    int t = threadIdx.x & 127;
    int node = blockIdx.x * 2 + half;
    if (node < n) {
        for (int i = t; i < 384; i += 128) ag[half][i] = agg[(long)node * 384 + i];
        for (int i = t; i < 160; i += 128) sv[half][i] = nf[(long)node * 160 + i];
    }
    __syncthreads();
    if (node >= n) return;

    const float c96 = 0.10206207261596577f;  // 1/sqrt(96)
    float osv = 0.f, ovv = 0.f;
    int k = t & 31, c = t >> 5;
    if (t < 96) {
        float a = 0.f;
        #pragma unroll 4
        for (int i = 0; i < 96; ++i) a += ag[half][i] * W2s[i * 96 + t];
        float b = 0.f;
        #pragma unroll 4
        for (int i = 0; i < 64; ++i) b += sv[half][i] * Wscs[i * 96 + t];
        osv = a * c96 + b * 0.125f;
        float av = 0.f;
        #pragma unroll 4
        for (int m = 0; m < 96; ++m) av += ag[half][96 + 3 * m + c] * W2v[m * 32 + k];
        float bv = 0.f;
        #pragma unroll 4
        for (int m = 0; m < 32; ++m) bv += sv[half][64 + 3 * m + c] * Wscv[m * 32 + k];
        ovv = av * c96 + bv * 0.17677669529663687f;
        if (t >= 64) gsrc[half][t - 64] = osv;
    }
    __syncthreads();
    if (t < 64) out[(long)node * 160 + t] = sv[half][t] + silu_f(osv);
    if (t < 96) {
        float g = silu_f(gsrc[half][k]);
        out[(long)node * 160 + 64 + 3 * k + c] = sv[half][64 + 3 * k + c] + ovv * g;
    }
}

extern "C" void kernel_launch(void* const* d_in, const int* in_sizes, int n_in,
                              void* d_out, int out_size, void* d_ws, size_t ws_size,
                              hipStream_t stream)
{
    const float* nf   = (const float*)d_in[0];
    const float* esh  = (const float*)d_in[1];
    const float* eemb = (const float*)d_in[2];
    const float* W1s  = (const float*)d_in[3];
    const float* W1v  = (const float*)d_in[4];
    const float* fcw1 = (const float*)d_in[5];
    const float* fcb1 = (const float*)d_in[6];
    const float* fcw2 = (const float*)d_in[7];
    const float* fcb2 = (const float*)d_in[8];
    const float* W2s  = (const float*)d_in[9];
    const float* W2v  = (const float*)d_in[10];
    const float* Wscs = (const float*)d_in[11];
    const float* Wscv = (const float*)d_in[12];
    const int*   ei   = (const int*)d_in[13];
    float* out = (float*)d_out;

    int nN = in_sizes[0] / 160;
    int nE = in_sizes[13] / 2;

    float* xs  = (float*)d_ws;
    float* xv  = xs + (size_t)nN * 64;
    float* agg = xv + (size_t)nN * 96;

    hipMemsetAsync(agg, 0, (size_t)nN * 384 * sizeof(float), stream);
    k_node_pre<<<(nN + 3) / 4, 256, 0, stream>>>(nf, W1s, W1v, xs, xv, nN);
    k_edge<<<(nE + TPB - 1) / TPB, TPB, 0, stream>>>(esh, eemb, fcw1, fcb1, fcw2, fcb2, ei, xs, xv, agg, nE);
    k_node_post<<<(nN + 1) / 2, 256, 0, stream>>>(nf, agg, W2s, W2v, Wscs, Wscv, out, nN);
}

// Round 2
// 1392.657 us; speedup vs baseline: 11.3687x; 11.3687x over previous
//
#include <hip/hip_runtime.h>
#include <math.h>

#define TPB 256
#define GB 192

__device__ __forceinline__ float silu_f(float x) { return x / (1.f + __expf(-x)); }

// ---------------- node pre: xs = s@W1_s/8, xv = v@W1_v/sqrt(32) ----------------
__global__ __launch_bounds__(256) void k_node_pre(
    const float* __restrict__ nf, const float* __restrict__ W1s, const float* __restrict__ W1v,
    float* __restrict__ xs, float* __restrict__ xv, int n)
{
    __shared__ float s_lds[4][64];
    __shared__ float v_lds[4][96];
    int w = threadIdx.x >> 6, l = threadIdx.x & 63;
    int node = blockIdx.x * 4 + w;
    if (node < n) {
        const float* row = nf + (long)node * 160;
        s_lds[w][l] = row[l];
        v_lds[w][l] = row[64 + l];
        if (l < 32) v_lds[w][64 + l] = row[128 + l];
    }
    __syncthreads();
    if (node >= n) return;
    float a = 0.f;
    #pragma unroll 8
    for (int i = 0; i < 64; ++i) a += s_lds[w][i] * W1s[i * 64 + l];
    xs[(long)node * 64 + l] = a * 0.125f;

    int k = l >> 1, c = l & 1;
    float b = 0.f;
    #pragma unroll 8
    for (int m = 0; m < 32; ++m) b += v_lds[w][m * 3 + c] * W1v[m * 32 + k];
    xv[(long)node * 96 + k * 3 + c] = b * 0.17677669529663687f;
    if (l < 32) {
        float d = 0.f;
        #pragma unroll 8
        for (int m = 0; m < 32; ++m) d += v_lds[w][m * 3 + 2] * W1v[m * 32 + l];
        xv[(long)node * 96 + l * 3 + 2] = d * 0.17677669529663687f;
    }
}

// ---------------- sort: histogram / scan / scatter ----------------
__global__ __launch_bounds__(256) void k_hist(const int* __restrict__ ei, int* __restrict__ deg, int nE)
{
    int e = blockIdx.x * 256 + threadIdx.x;
    if (e < nE) atomicAdd(&deg[ei[nE + e]], 1);
}

__global__ __launch_bounds__(256) void k_scan1(const int* __restrict__ deg, int* __restrict__ incl,
                                               int* __restrict__ partials, int nN)
{
    __shared__ int lds[256];
    int t = threadIdx.x;
    int base = blockIdx.x * 1024;
    int v[4]; int s = 0;
    #pragma unroll
    for (int q = 0; q < 4; ++q) { int idx = base + t * 4 + q; v[q] = (idx < nN) ? deg[idx] : 0; s += v[q]; }
    lds[t] = s; __syncthreads();
    #pragma unroll
    for (int off = 1; off < 256; off <<= 1) {
        int x = (t >= off) ? lds[t - off] : 0;
        __syncthreads();
        lds[t] += x;
        __syncthreads();
    }
    int inclT = lds[t];
    if (t == 255) partials[blockIdx.x] = inclT;
    int run = inclT - s;
    #pragma unroll
    for (int q = 0; q < 4; ++q) { run += v[q]; int idx = base + t * 4 + q; if (idx < nN) incl[idx] = run; }
}

__global__ void k_scan2(int* partials, int nb)
{
    if (threadIdx.x == 0 && blockIdx.x == 0) {
        int run = 0;
        for (int i = 0; i < nb; ++i) { int x = partials[i]; partials[i] = run; run += x; }
    }
}

__global__ __launch_bounds__(256) void k_scan3(const int* __restrict__ incl, const int* __restrict__ deg,
                                               const int* __restrict__ partials,
                                               int* __restrict__ offs, int* __restrict__ cursor, int nN)
{
    int i = blockIdx.x * 256 + threadIdx.x;
    if (i < nN) {
        int excl = incl[i] - deg[i] + partials[i >> 10];
        offs[i] = excl; cursor[i] = excl;
    }
}

__global__ __launch_bounds__(256) void k_scatter(const int* __restrict__ ei, int* __restrict__ cursor,
                                                 int* __restrict__ sorted, int nE)
{
    int e = blockIdx.x * 256 + threadIdx.x;
    if (e < nE) {
        int d = ei[nE + e];
        int pos = atomicAdd(&cursor[d], 1);
        sorted[pos] = e;
    }
}

// ---------------- gather: per-node edge MLP + message accumulate ----------------
// block = 192 threads (3 waves). Thread t owns MLP column t.
//   t in [0,64):    m0_a slot t            (w_ss col t)
//   t in [64,128):  m1_a slots for j=t-64  (w_sv col t)
//   t in [128,160): m1_b slots for k=t-128 (w_vs col t)
//   t in [160,192): m0_b slot  for k=t-160 (w_vv col t)
__global__ __launch_bounds__(192) void k_gather(
    const float* __restrict__ esh, const float* __restrict__ eemb,
    const float* __restrict__ fcw1, const float* __restrict__ fcb1,
    const float* __restrict__ fcw2, const float* __restrict__ fcb2,
    const int* __restrict__ ei,
    const float* __restrict__ xs, const float* __restrict__ xv,
    const int* __restrict__ offs, const int* __restrict__ deg,
    const int* __restrict__ sorted, float* __restrict__ agg, int nN, int nE)
{
    __shared__ float w1s[512];
    __shared__ float b1s_[64];
    __shared__ float hid[2][3][64];
    __shared__ float meta[2][3][8];   // [0]=src(bits) [1]=sh0 [2..4]=sh1xyz

    int t = threadIdx.x;
    for (int i = t; i < 512; i += GB) w1s[i] = fcw1[i];
    if (t < 64) b1s_[t] = fcb1[t];

    float wcol[64];
    #pragma unroll
    for (int h = 0; h < 64; ++h) wcol[h] = fcw2[h * 192 + t];
    float b2 = fcb2[t];
    __syncthreads();

    int b = t >> 6;       // edge slot in batch (0..2)
    int h = t & 63;       // hidden unit
    const float qdeg = 0.25f;             // 1/sqrt(16)
    const float inv_s3 = 0.57735026918962576f;

    for (int node = blockIdx.x; node < nN; node += gridDim.x) {
        int start = offs[node];
        int cnt = deg[node];
        float acc0 = 0.f, acc1 = 0.f, acc2 = 0.f;
        int buf = 0;

        for (int i0 = 0; i0 < cnt; i0 += 3) {
            int idx = i0 + b;
            if (idx < cnt) {
                int eid = sorted[start + idx];
                const float4* pe = (const float4*)(eemb + (long)eid * 8);
                float4 u = pe[0], v2 = pe[1];
                float a = b1s_[h];
                a += u.x  * w1s[h]       + u.y  * w1s[64 + h]  + u.z  * w1s[128 + h] + u.w  * w1s[192 + h];
                a += v2.x * w1s[256 + h] + v2.y * w1s[320 + h] + v2.z * w1s[384 + h] + v2.w * w1s[448 + h];
                hid[buf][b][h] = silu_f(a);
                if (h == 0) {
                    int s_ = ei[eid];
                    float4 sh = *(const float4*)(esh + (long)eid * 4);
                    meta[buf][b][0] = __int_as_float(s_);
                    meta[buf][b][1] = sh.x * qdeg;
                    meta[buf][b][2] = sh.y * qdeg;
                    meta[buf][b][3] = sh.z * qdeg;
                    meta[buf][b][4] = sh.w * qdeg;
                }
            }
            __syncthreads();

            int nb_ = cnt - i0; if (nb_ > 3) nb_ = 3;
            for (int bb = 0; bb < nb_; ++bb) {
                int src = __float_as_int(meta[buf][bb][0]);
                float sh0 = meta[buf][bb][1];
                float s1x = meta[buf][bb][2], s1y = meta[buf][bb][3], s1z = meta[buf][bb][4];
                float dot = b2;
                const float* hp = hid[buf][bb];
                #pragma unroll
                for (int q = 0; q < 64; ++q) dot += hp[q] * wcol[q];

                if (t < 64) {
                    float f = xs[(long)src * 64 + t];
                    acc0 += dot * f * sh0;
                } else if (t < 128) {
                    float xsj = xs[(long)src * 64 + (t - 64)];
                    float tt = dot * xsj;
                    acc0 += tt * s1x; acc1 += tt * s1y; acc2 += tt * s1z;
                } else if (t < 160) {
                    const float* xr = xv + (long)src * 96 + 3 * (t - 128);
                    acc0 += dot * xr[0] * sh0;
                    acc1 += dot * xr[1] * sh0;
                    acc2 += dot * xr[2] * sh0;
                } else {
                    const float* xr = xv + (long)src * 96 + 3 * (t - 160);
                    float dv = xr[0] * s1x + xr[1] * s1y + xr[2] * s1z;
                    acc0 += dot * dv * inv_s3;
                }
            }
            buf ^= 1;
        }

        float* row = agg + (long)node * 384;
        if (t < 64) {
            row[t] = acc0;
        } else if (t < 128) {
            int j = t - 64;
            row[96 + 3 * j] = acc0; row[96 + 3 * j + 1] = acc1; row[96 + 3 * j + 2] = acc2;
        } else if (t < 160) {
            int k = t - 128;
            row[288 + 3 * k] = acc0; row[288 + 3 * k + 1] = acc1; row[288 + 3 * k + 2] = acc2;
        } else {
            row[64 + (t - 160)] = acc0;
        }
    }
}

// ---------------- node post: linear + gating + residual ----------------
__global__ __launch_bounds__(256) void k_node_post(
    const float* __restrict__ nf, const float* __restrict__ agg,
    const float* __restrict__ W2s, const float* __restrict__ W2v,
    const float* __restrict__ Wscs, const float* __restrict__ Wscv,
    float* __restrict__ out, int n)
{
    __shared__ float ag[2][384];
    __shared__ float sv[2][160];
    __shared__ float gsrc[2][32];
    int half = threadIdx.x >> 7;
    int t = threadIdx.x & 127;
    int node = blockIdx.x * 2 + half;
    if (node < n) {
        for (int i = t; i < 384; i += 128) ag[half][i] = agg[(long)node * 384 + i];
        for (int i = t; i < 160; i += 128) sv[half][i] = nf[(long)node * 160 + i];
    }
    __syncthreads();
    if (node >= n) return;

    const float c96 = 0.10206207261596577f;  // 1/sqrt(96)
    float osv = 0.f, ovv = 0.f;
    int k = t & 31, c = t >> 5;
    if (t < 96) {
        float a = 0.f;
        #pragma unroll 4
        for (int i = 0; i < 96; ++i) a += ag[half][i] * W2s[i * 96 + t];
        float b = 0.f;
        #pragma unroll 4
        for (int i = 0; i < 64; ++i) b += sv[half][i] * Wscs[i * 96 + t];
        osv = a * c96 + b * 0.125f;
        float av = 0.f;
        #pragma unroll 4
        for (int m = 0; m < 96; ++m) av += ag[half][96 + 3 * m + c] * W2v[m * 32 + k];
        float bv = 0.f;
        #pragma unroll 4
        for (int m = 0; m < 32; ++m) bv += sv[half][64 + 3 * m + c] * Wscv[m * 32 + k];
        ovv = av * c96 + bv * 0.17677669529663687f;
        if (t >= 64) gsrc[half][t - 64] = osv;
    }
    __syncthreads();
    if (t < 64) out[(long)node * 160 + t] = sv[half][t] + silu_f(osv);
    if (t < 96) {
        float g = silu_f(gsrc[half][k]);
        out[(long)node * 160 + 64 + 3 * k + c] = sv[half][64 + 3 * k + c] + ovv * g;
    }
}

extern "C" void kernel_launch(void* const* d_in, const int* in_sizes, int n_in,
                              void* d_out, int out_size, void* d_ws, size_t ws_size,
                              hipStream_t stream)
{
    const float* nf   = (const float*)d_in[0];
    const float* esh  = (const float*)d_in[1];
    const float* eemb = (const float*)d_in[2];
    const float* W1s  = (const float*)d_in[3];
    const float* W1v  = (const float*)d_in[4];
    const float* fcw1 = (const float*)d_in[5];
    const float* fcb1 = (const float*)d_in[6];
    const float* fcw2 = (const float*)d_in[7];
    const float* fcb2 = (const float*)d_in[8];
    const float* W2s  = (const float*)d_in[9];
    const float* W2v  = (const float*)d_in[10];
    const float* Wscs = (const float*)d_in[11];
    const float* Wscv = (const float*)d_in[12];
    const int*   ei   = (const int*)d_in[13];
    float* out = (float*)d_out;

    int nN = in_sizes[0] / 160;
    int nE = in_sizes[13] / 2;

    float* xs   = (float*)d_ws;
    float* xv   = xs + (size_t)nN * 64;
    float* agg  = xv + (size_t)nN * 96;
    int* deg    = (int*)(agg + (size_t)nN * 384);
    int* offs   = deg + nN;
    int* cursor = offs + nN;
    int* incl   = cursor + nN;
    int* sorted = incl + nN;
    int* partials = sorted + nE;

    int nb1 = (nN + 1023) / 1024;

    hipMemsetAsync(deg, 0, (size_t)nN * sizeof(int), stream);
    k_node_pre<<<(nN + 3) / 4, 256, 0, stream>>>(nf, W1s, W1v, xs, xv, nN);
    k_hist<<<(nE + 255) / 256, 256, 0, stream>>>(ei, deg, nE);
    k_scan1<<<nb1, 256, 0, stream>>>(deg, incl, partials, nN);
    k_scan2<<<1, 64, 0, stream>>>(partials, nb1);
    k_scan3<<<(nN + 255) / 256, 256, 0, stream>>>(incl, deg, partials, offs, cursor, nN);
    k_scatter<<<(nE + 255) / 256, 256, 0, stream>>>(ei, cursor, sorted, nE);
    k_gather<<<2048, GB, 0, stream>>>(esh, eemb, fcw1, fcb1, fcw2, fcb2, ei,
                                      xs, xv, offs, deg, sorted, agg, nN, nE);
    k_node_post<<<(nN + 1) / 2, 256, 0, stream>>>(nf, agg, W2s, W2v, Wscs, Wscv, out, nN);
}

// Round 3
// 816.856 us; speedup vs baseline: 19.3825x; 1.7049x over previous
//
#include <hip/hip_runtime.h>
#include <math.h>

typedef float f32x4 __attribute__((ext_vector_type(4)));
typedef short short8 __attribute__((ext_vector_type(8)));

__device__ __forceinline__ float silu_f(float x) { return x / (1.f + __expf(-x)); }

__device__ __forceinline__ unsigned short f2bf(float x) {
    unsigned u = __float_as_uint(x);
    unsigned r = (u + 0x7fffu + ((u >> 16) & 1u)) >> 16;
    return (unsigned short)r;
}

// ---------------- node pre: xs = s@W1_s/8, xv = v@W1_v/sqrt(32) ----------------
__global__ __launch_bounds__(256) void k_node_pre(
    const float* __restrict__ nf, const float* __restrict__ W1s, const float* __restrict__ W1v,
    float* __restrict__ xs, float* __restrict__ xv, int n)
{
    __shared__ float s_lds[4][64];
    __shared__ float v_lds[4][96];
    int w = threadIdx.x >> 6, l = threadIdx.x & 63;
    int node = blockIdx.x * 4 + w;
    if (node < n) {
        const float* row = nf + (long)node * 160;
        s_lds[w][l] = row[l];
        v_lds[w][l] = row[64 + l];
        if (l < 32) v_lds[w][64 + l] = row[128 + l];
    }
    __syncthreads();
    if (node >= n) return;
    float a = 0.f;
    #pragma unroll 8
    for (int i = 0; i < 64; ++i) a += s_lds[w][i] * W1s[i * 64 + l];
    xs[(long)node * 64 + l] = a * 0.125f;

    int k = l >> 1, c = l & 1;
    float b = 0.f;
    #pragma unroll 8
    for (int m = 0; m < 32; ++m) b += v_lds[w][m * 3 + c] * W1v[m * 32 + k];
    xv[(long)node * 96 + k * 3 + c] = b * 0.17677669529663687f;
    if (l < 32) {
        float d = 0.f;
        #pragma unroll 8
        for (int m = 0; m < 32; ++m) d += v_lds[w][m * 3 + 2] * W1v[m * 32 + l];
        xv[(long)node * 96 + l * 3 + 2] = d * 0.17677669529663687f;
    }
}

// ---------------- sort: histogram / scan / scatter ----------------
__global__ __launch_bounds__(256) void k_hist(const int* __restrict__ ei, int* __restrict__ deg, int nE)
{
    int e = blockIdx.x * 256 + threadIdx.x;
    if (e < nE) atomicAdd(&deg[ei[nE + e]], 1);
}

__global__ __launch_bounds__(256) void k_scan1(const int* __restrict__ deg, int* __restrict__ incl,
                                               int* __restrict__ partials, int nN)
{
    __shared__ int lds[256];
    int t = threadIdx.x;
    int base = blockIdx.x * 1024;
    int v[4]; int s = 0;
    #pragma unroll
    for (int q = 0; q < 4; ++q) { int idx = base + t * 4 + q; v[q] = (idx < nN) ? deg[idx] : 0; s += v[q]; }
    lds[t] = s; __syncthreads();
    #pragma unroll
    for (int off = 1; off < 256; off <<= 1) {
        int x = (t >= off) ? lds[t - off] : 0;
        __syncthreads();
        lds[t] += x;
        __syncthreads();
    }
    int inclT = lds[t];
    if (t == 255) partials[blockIdx.x] = inclT;
    int run = inclT - s;
    #pragma unroll
    for (int q = 0; q < 4; ++q) { run += v[q]; int idx = base + t * 4 + q; if (idx < nN) incl[idx] = run; }
}

__global__ void k_scan2(int* partials, int nb)
{
    if (threadIdx.x == 0 && blockIdx.x == 0) {
        int run = 0;
        for (int i = 0; i < nb; ++i) { int x = partials[i]; partials[i] = run; run += x; }
    }
}

__global__ __launch_bounds__(256) void k_scan3(const int* __restrict__ incl, const int* __restrict__ deg,
                                               const int* __restrict__ partials,
                                               int* __restrict__ offs, int* __restrict__ cursor, int nN)
{
    int i = blockIdx.x * 256 + threadIdx.x;
    if (i < nN) {
        int excl = incl[i] - deg[i] + partials[i >> 10];
        offs[i] = excl; cursor[i] = excl;
    }
}

__global__ __launch_bounds__(256) void k_scatter(const int* __restrict__ ei, int* __restrict__ cursor,
                                                 int* __restrict__ sorted, int nE)
{
    int e = blockIdx.x * 256 + threadIdx.x;
    if (e < nE) {
        int d = ei[nE + e];
        int pos = atomicAdd(&cursor[d], 1);
        sorted[pos] = e;
    }
}

// ---------------- gather with MFMA layer-2 ----------------
// 256 threads = 4 waves. Per node, per 16-edge batch:
//   meta load (t<16) -> layer-1 hid (bf16, swizzled LDS) -> 6 MFMA/wave
//   (3 col-tiles x K=64) -> per-lane register accumulate into node slots.
// Wave w owns output cols [w*48, w*48+48): tile rt=w*3+tt; regions align to
// 16-col tiles: rt 0-3 m0_a, 4-7 m1_a, 8-9 m1_b, 10-11 m0_b.
__global__ __launch_bounds__(256, 4) void k_gather_mfma(
    const float* __restrict__ esh, const float* __restrict__ eemb,
    const float* __restrict__ fcw1, const float* __restrict__ fcb1,
    const float* __restrict__ fcw2, const float* __restrict__ fcb2,
    const int* __restrict__ ei,
    const float* __restrict__ xs, const float* __restrict__ xv,
    const int* __restrict__ offs, const int* __restrict__ deg,
    const int* __restrict__ sorted, float* __restrict__ agg, int nN)
{
    __shared__ unsigned short hid_lds[2][1024];  // [16 edges][64 hid] bf16, XOR-swizzled
    __shared__ float meta[2][16][16];            // [e]: 0=src 1=sh0 2-4=sh1 8-15=ee

    const int t = threadIdx.x;
    const int l = t & 63;
    const int w = t >> 6;
    const int lr = l & 15;   // A-row / B,C-col within tile
    const int lg = l >> 4;   // k-group / C-row-group

    // layer-1 weights for this thread's hidden unit
    const int myh = l;
    float w1r[8];
    #pragma unroll
    for (int b = 0; b < 8; ++b) w1r[b] = fcw1[b * 64 + myh];
    const float b1r = fcb1[myh];

    // B fragments: B[k][j], j = lane&15 within tile, k = kk*32 + lg*8 + b
    short8 bfrag[3][2];
    #pragma unroll
    for (int tt = 0; tt < 3; ++tt) {
        int j = w * 48 + tt * 16 + lr;
        #pragma unroll
        for (int kk = 0; kk < 2; ++kk) {
            short8 f;
            #pragma unroll
            for (int b = 0; b < 8; ++b) {
                int k = kk * 32 + lg * 8 + b;
                f[b] = (short)f2bf(fcw2[k * 192 + j]);
            }
            bfrag[tt][kk] = f;
        }
    }

    const float qdeg = 0.25f;  // 1/sqrt(avg_deg=16)
    const float inv_s3 = 0.57735026918962576f;

    for (int node = blockIdx.x; node < nN; node += gridDim.x) {
        const int start = offs[node];
        const int cnt = deg[node];

        float acc[3][3];
        #pragma unroll
        for (int tt = 0; tt < 3; ++tt) { acc[tt][0] = 0.f; acc[tt][1] = 0.f; acc[tt][2] = 0.f; }

        int buf = 0;
        for (int i0 = 0; i0 < cnt; i0 += 16) {
            if (t < 16) {
                int i = i0 + t;
                bool valid = i < cnt;
                int eid = sorted[start + (valid ? i : 0)];
                int s_ = ei[eid];
                float4 sh = make_float4(0.f, 0.f, 0.f, 0.f);
                if (valid) sh = *(const float4*)(esh + (size_t)eid * 4);
                const float4* pe = (const float4*)(eemb + (size_t)eid * 8);
                float4 e0 = pe[0], e1 = pe[1];
                float* m = &meta[buf][t][0];
                m[0] = __int_as_float(s_);
                m[1] = sh.x * qdeg; m[2] = sh.y * qdeg; m[3] = sh.z * qdeg; m[4] = sh.w * qdeg;
                *(float4*)(m + 8) = e0;
                *(float4*)(m + 12) = e1;
            }
            __syncthreads();

            // layer-1: each thread computes hidden unit myh for 4 edges
            #pragma unroll
            for (int q = 0; q < 4; ++q) {
                int e = w * 4 + q;
                const float* m = &meta[buf][e][0];
                float a = b1r;
                a += m[8]  * w1r[0] + m[9]  * w1r[1] + m[10] * w1r[2] + m[11] * w1r[3];
                a += m[12] * w1r[4] + m[13] * w1r[5] + m[14] * w1r[6] + m[15] * w1r[7];
                float s = a / (1.f + __expf(-a));
                hid_lds[buf][e * 64 + (myh ^ ((e & 7) << 3))] = f2bf(s);
            }
            __syncthreads();

            // A fragments: A[row=lr][k = kk*32 + lg*8 + b], swizzled read (2-way max)
            short8 a0 = *(const short8*)&hid_lds[buf][lr * 64 + (((0 * 32) + lg * 8) ^ ((lr & 7) << 3))];
            short8 a1 = *(const short8*)&hid_lds[buf][lr * 64 + (((1 * 32) + lg * 8) ^ ((lr & 7) << 3))];

            f32x4 c0 = {0.f, 0.f, 0.f, 0.f}, c1 = c0, c2 = c0;
            c0 = __builtin_amdgcn_mfma_f32_16x16x32_bf16(a0, bfrag[0][0], c0, 0, 0, 0);
            c0 = __builtin_amdgcn_mfma_f32_16x16x32_bf16(a1, bfrag[0][1], c0, 0, 0, 0);
            c1 = __builtin_amdgcn_mfma_f32_16x16x32_bf16(a0, bfrag[1][0], c1, 0, 0, 0);
            c1 = __builtin_amdgcn_mfma_f32_16x16x32_bf16(a1, bfrag[1][1], c1, 0, 0, 0);
            c2 = __builtin_amdgcn_mfma_f32_16x16x32_bf16(a0, bfrag[2][0], c2, 0, 0, 0);
            c2 = __builtin_amdgcn_mfma_f32_16x16x32_bf16(a1, bfrag[2][1], c2, 0, 0, 0);

            // combine: C row (lg*4+r) = edge slot, col = tile col lr
            #pragma unroll
            for (int r = 0; r < 4; ++r) {
                int er = lg * 4 + r;
                const float* m = &meta[buf][er][0];
                int src = __float_as_int(m[0]);
                float sh0 = m[1], s1x = m[2], s1y = m[3], s1z = m[4];
                const float* xsrow = xs + (size_t)src * 64;
                const float* xvrow = xv + (size_t)src * 96;
                #pragma unroll
                for (int tt = 0; tt < 3; ++tt) {
                    float val = (tt == 0) ? c0[r] : ((tt == 1) ? c1[r] : c2[r]);
                    int rtt = w * 3 + tt;
                    if (rtt < 4) {                      // m0_a
                        int j = rtt * 16 + lr;
                        acc[tt][0] += val * xsrow[j] * sh0;
                    } else if (rtt < 8) {               // m1_a
                        int j = (rtt - 4) * 16 + lr;
                        float tmp = val * xsrow[j];
                        acc[tt][0] += tmp * s1x; acc[tt][1] += tmp * s1y; acc[tt][2] += tmp * s1z;
                    } else if (rtt < 10) {              // m1_b
                        int k = (rtt - 8) * 16 + lr;
                        float v0 = xvrow[3 * k], v1 = xvrow[3 * k + 1], v2 = xvrow[3 * k + 2];
                        float tmp = val * sh0;
                        acc[tt][0] += tmp * v0; acc[tt][1] += tmp * v1; acc[tt][2] += tmp * v2;
                    } else {                            // m0_b
                        int k = (rtt - 10) * 16 + lr;
                        float v0 = xvrow[3 * k], v1 = xvrow[3 * k + 1], v2 = xvrow[3 * k + 2];
                        float dv = v0 * s1x + v1 * s1y + v2 * s1z;
                        acc[tt][0] += val * dv * inv_s3;
                    }
                }
            }
            buf ^= 1;
        }

        // reduce across row-groups (lanes xor 16, 32) and write agg row
        float* row = agg + (size_t)node * 384;
        #pragma unroll
        for (int tt = 0; tt < 3; ++tt) {
            int rtt = w * 3 + tt;
            if (rtt < 4) {
                float v = acc[tt][0]; v += __shfl_xor(v, 16); v += __shfl_xor(v, 32);
                if (l < 16) row[rtt * 16 + l] = v;
            } else if (rtt < 8) {
                float vx = acc[tt][0]; vx += __shfl_xor(vx, 16); vx += __shfl_xor(vx, 32);
                float vy = acc[tt][1]; vy += __shfl_xor(vy, 16); vy += __shfl_xor(vy, 32);
                float vz = acc[tt][2]; vz += __shfl_xor(vz, 16); vz += __shfl_xor(vz, 32);
                if (l < 16) {
                    int j = (rtt - 4) * 16 + l;
                    row[96 + 3 * j] = vx; row[96 + 3 * j + 1] = vy; row[96 + 3 * j + 2] = vz;
                }
            } else if (rtt < 10) {
                float vx = acc[tt][0]; vx += __shfl_xor(vx, 16); vx += __shfl_xor(vx, 32);
                float vy = acc[tt][1]; vy += __shfl_xor(vy, 16); vy += __shfl_xor(vy, 32);
                float vz = acc[tt][2]; vz += __shfl_xor(vz, 16); vz += __shfl_xor(vz, 32);
                if (l < 16) {
                    int k = (rtt - 8) * 16 + l;
                    row[288 + 3 * k] = vx; row[288 + 3 * k + 1] = vy; row[288 + 3 * k + 2] = vz;
                }
            } else {
                float v = acc[tt][0]; v += __shfl_xor(v, 16); v += __shfl_xor(v, 32);
                if (l < 16) row[64 + (rtt - 10) * 16 + l] = v;
            }
        }
    }
}

// ---------------- node post: linear + gating + residual ----------------
__global__ __launch_bounds__(256) void k_node_post(
    const float* __restrict__ nf, const float* __restrict__ agg,
    const float* __restrict__ W2s, const float* __restrict__ W2v,
    const float* __restrict__ Wscs, const float* __restrict__ Wscv,
    float* __restrict__ out, int n)
{
    __shared__ float ag[2][384];
    __shared__ float sv[2][160];
    __shared__ float gsrc[2][32];
    int half = threadIdx.x >> 7;
    int t = threadIdx.x & 127;
    int node = blockIdx.x * 2 + half;
    if (node < n) {
        for (int i = t; i < 384; i += 128) ag[half][i] = agg[(long)node * 384 + i];
        for (int i = t; i < 160; i += 128) sv[half][i] = nf[(long)node * 160 + i];
    }
    __syncthreads();
    if (node >= n) return;

    const float c96 = 0.10206207261596577f;  // 1/sqrt(96)
    float osv = 0.f, ovv = 0.f;
    int k = t & 31, c = t >> 5;
    if (t < 96) {
        float a = 0.f;
        #pragma unroll 4
        for (int i = 0; i < 96; ++i) a += ag[half][i] * W2s[i * 96 + t];
        float b = 0.f;
        #pragma unroll 4
        for (int i = 0; i < 64; ++i) b += sv[half][i] * Wscs[i * 96 + t];
        osv = a * c96 + b * 0.125f;
        float av = 0.f;
        #pragma unroll 4
        for (int m = 0; m < 96; ++m) av += ag[half][96 + 3 * m + c] * W2v[m * 32 + k];
        float bv = 0.f;
        #pragma unroll 4
        for (int m = 0; m < 32; ++m) bv += sv[half][64 + 3 * m + c] * Wscv[m * 32 + k];
        ovv = av * c96 + bv * 0.17677669529663687f;
        if (t >= 64) gsrc[half][t - 64] = osv;
    }
    __syncthreads();
    if (t < 64) out[(long)node * 160 + t] = sv[half][t] + silu_f(osv);
    if (t < 96) {
        float g = silu_f(gsrc[half][k]);
        out[(long)node * 160 + 64 + 3 * k + c] = sv[half][64 + 3 * k + c] + ovv * g;
    }
}

extern "C" void kernel_launch(void* const* d_in, const int* in_sizes, int n_in,
                              void* d_out, int out_size, void* d_ws, size_t ws_size,
                              hipStream_t stream)
{
    const float* nf   = (const float*)d_in[0];
    const float* esh  = (const float*)d_in[1];
    const float* eemb = (const float*)d_in[2];
    const float* W1s  = (const float*)d_in[3];
    const float* W1v  = (const float*)d_in[4];
    const float* fcw1 = (const float*)d_in[5];
    const float* fcb1 = (const float*)d_in[6];
    const float* fcw2 = (const float*)d_in[7];
    const float* fcb2 = (const float*)d_in[8];
    const float* W2s  = (const float*)d_in[9];
    const float* W2v  = (const float*)d_in[10];
    const float* Wscs = (const float*)d_in[11];
    const float* Wscv = (const float*)d_in[12];
    const int*   ei   = (const int*)d_in[13];
    float* out = (float*)d_out;

    int nN = in_sizes[0] / 160;
    int nE = in_sizes[13] / 2;

    float* xs   = (float*)d_ws;
    float* xv   = xs + (size_t)nN * 64;
    float* agg  = xv + (size_t)nN * 96;
    int* deg    = (int*)(agg + (size_t)nN * 384);
    int* offs   = deg + nN;
    int* cursor = offs + nN;
    int* incl   = cursor + nN;
    int* sorted = incl + nN;
    int* partials = sorted + nE;

    int nb1 = (nN + 1023) / 1024;

    hipMemsetAsync(deg, 0, (size_t)nN * sizeof(int), stream);
    k_node_pre<<<(nN + 3) / 4, 256, 0, stream>>>(nf, W1s, W1v, xs, xv, nN);
    k_hist<<<(nE + 255) / 256, 256, 0, stream>>>(ei, deg, nE);
    k_scan1<<<nb1, 256, 0, stream>>>(deg, incl, partials, nN);
    k_scan2<<<1, 64, 0, stream>>>(partials, nb1);
    k_scan3<<<(nN + 255) / 256, 256, 0, stream>>>(incl, deg, partials, offs, cursor, nN);
    k_scatter<<<(nE + 255) / 256, 256, 0, stream>>>(ei, cursor, sorted, nE);
    k_gather_mfma<<<2048, 256, 0, stream>>>(esh, eemb, fcw1, fcb1, fcw2, fcb2, ei,
                                            xs, xv, offs, deg, sorted, agg, nN);
    k_node_post<<<(nN + 1) / 2, 256, 0, stream>>>(nf, agg, W2s, W2v, Wscs, Wscv, out, nN);
}

// Round 7
// 744.283 us; speedup vs baseline: 21.2724x; 1.0975x over previous
//
#include <hip/hip_runtime.h>
#include <math.h>

typedef float f32x4 __attribute__((ext_vector_type(4)));
typedef short short8 __attribute__((ext_vector_type(8)));

__device__ __forceinline__ float silu_f(float x) { return x / (1.f + __expf(-x)); }

__device__ __forceinline__ unsigned short f2bf(float x) {
    unsigned u = __float_as_uint(x);
    unsigned r = (u + 0x7fffu + ((u >> 16) & 1u)) >> 16;
    return (unsigned short)r;
}

// ---------------- node pre: xs = s@W1_s/8, xv = v@W1_v/sqrt(32) (f32) ----------------
__global__ __launch_bounds__(256) void k_node_pre(
    const float* __restrict__ nf, const float* __restrict__ W1s, const float* __restrict__ W1v,
    float* __restrict__ xs, float* __restrict__ xv, int n)
{
    __shared__ float s_lds[4][64];
    __shared__ float v_lds[4][96];
    int w = threadIdx.x >> 6, l = threadIdx.x & 63;
    int node = blockIdx.x * 4 + w;
    if (node < n) {
        const float* row = nf + (long)node * 160;
        s_lds[w][l] = row[l];
        v_lds[w][l] = row[64 + l];
        if (l < 32) v_lds[w][64 + l] = row[128 + l];
    }
    __syncthreads();
    if (node >= n) return;
    float a = 0.f;
    #pragma unroll 8
    for (int i = 0; i < 64; ++i) a += s_lds[w][i] * W1s[i * 64 + l];
    xs[(long)node * 64 + l] = a * 0.125f;

    int k = l >> 1, c = l & 1;
    float b = 0.f;
    #pragma unroll 8
    for (int m = 0; m < 32; ++m) b += v_lds[w][m * 3 + c] * W1v[m * 32 + k];
    xv[(long)node * 96 + k * 3 + c] = b * 0.17677669529663687f;
    if (l < 32) {
        float d = 0.f;
        #pragma unroll 8
        for (int m = 0; m < 32; ++m) d += v_lds[w][m * 3 + 2] * W1v[m * 32 + l];
        xv[(long)node * 96 + l * 3 + 2] = d * 0.17677669529663687f;
    }
}

// ---------------- sort: histogram / scan / scatter ----------------
__global__ __launch_bounds__(256) void k_hist(const int* __restrict__ ei, int* __restrict__ deg, int nE)
{
    int e = blockIdx.x * 256 + threadIdx.x;
    if (e < nE) atomicAdd(&deg[ei[nE + e]], 1);
}

__global__ __launch_bounds__(256) void k_scan1(const int* __restrict__ deg, int* __restrict__ incl,
                                               int* __restrict__ partials, int nN)
{
    __shared__ int lds[256];
    int t = threadIdx.x;
    int base = blockIdx.x * 1024;
    int v[4]; int s = 0;
    #pragma unroll
    for (int q = 0; q < 4; ++q) { int idx = base + t * 4 + q; v[q] = (idx < nN) ? deg[idx] : 0; s += v[q]; }
    lds[t] = s; __syncthreads();
    #pragma unroll
    for (int off = 1; off < 256; off <<= 1) {
        int x = (t >= off) ? lds[t - off] : 0;
        __syncthreads();
        lds[t] += x;
        __syncthreads();
    }
    int inclT = lds[t];
    if (t == 255) partials[blockIdx.x] = inclT;
    int run = inclT - s;
    #pragma unroll
    for (int q = 0; q < 4; ++q) { run += v[q]; int idx = base + t * 4 + q; if (idx < nN) incl[idx] = run; }
}

__global__ void k_scan2(int* partials, int nb)
{
    if (threadIdx.x == 0 && blockIdx.x == 0) {
        int run = 0;
        for (int i = 0; i < nb; ++i) { int x = partials[i]; partials[i] = run; run += x; }
    }
}

__global__ __launch_bounds__(256) void k_scan3(const int* __restrict__ incl, const int* __restrict__ deg,
                                               const int* __restrict__ partials,
                                               int* __restrict__ offs, int* __restrict__ cursor, int nN)
{
    int i = blockIdx.x * 256 + threadIdx.x;
    if (i < nN) {
        int excl = incl[i] - deg[i] + partials[i >> 10];
        offs[i] = excl; cursor[i] = excl;
    }
}

__global__ __launch_bounds__(256) void k_scatter(const int* __restrict__ ei, int* __restrict__ cursor,
                                                 int* __restrict__ sorted, int nE)
{
    int e = blockIdx.x * 256 + threadIdx.x;
    if (e < nE) {
        int d = ei[nE + e];
        int pos = atomicAdd(&cursor[d], 1);
        sorted[pos] = e;
    }
}

// ---------------- gather with MFMA layer-2 + double-buffered xs/xv LDS staging ----------------
__global__ __launch_bounds__(256, 4) void k_gather_mfma(
    const float* __restrict__ esh, const float* __restrict__ eemb,
    const float* __restrict__ fcw1, const float* __restrict__ fcb1,
    const float* __restrict__ fcw2, const float* __restrict__ fcb2,
    const int* __restrict__ ei,
    const float* __restrict__ xs, const float* __restrict__ xv,
    const int* __restrict__ offs, const int* __restrict__ deg,
    const int* __restrict__ sorted, float* __restrict__ agg, int nN)
{
    __shared__ unsigned short hid_lds[2][1024];  // [16 edges][64 hid] bf16, XOR-swizzled
    __shared__ float meta[2][16][16];            // [e]: 0=src 1-4=sh*qdeg 8-15=ee
    __shared__ float xsv[2][16][164];            // staged xs(64)+xv(96) f32 per edge (+pad)

    const int t = threadIdx.x;
    const int l = t & 63;
    const int w = t >> 6;
    const int lr = l & 15;
    const int lg = l >> 4;

    const int myh = l;
    float w1r[8];
    #pragma unroll
    for (int b = 0; b < 8; ++b) w1r[b] = fcw1[b * 64 + myh];
    const float b1r = fcb1[myh];

    short8 bfrag[3][2];
    #pragma unroll
    for (int tt = 0; tt < 3; ++tt) {
        int j = w * 48 + tt * 16 + lr;
        #pragma unroll
        for (int kk = 0; kk < 2; ++kk) {
            short8 f;
            #pragma unroll
            for (int b = 0; b < 8; ++b) {
                int k = kk * 32 + lg * 8 + b;
                f[b] = (short)f2bf(fcw2[k * 192 + j]);
            }
            bfrag[tt][kk] = f;
        }
    }

    const float qdeg = 0.25f;  // 1/sqrt(avg_deg=16)
    const float inv_s3 = 0.57735026918962576f;

    for (int node = blockIdx.x; node < nN; node += gridDim.x) {
        const int start = offs[node];
        const int cnt = deg[node];

        float acc[3][3];
        #pragma unroll
        for (int tt = 0; tt < 3; ++tt) { acc[tt][0] = 0.f; acc[tt][1] = 0.f; acc[tt][2] = 0.f; }

        // ---- helpers inlined: meta load + xsv stage ----
        // prologue: batch 0 into buffer 0
        if (cnt > 0) {
            if (t < 16) {
                int i = t;
                bool valid = i < cnt;
                int eid = sorted[start + (valid ? i : 0)];
                int s_ = ei[eid];
                float4 sh = make_float4(0.f, 0.f, 0.f, 0.f);
                if (valid) sh = *(const float4*)(esh + (size_t)eid * 4);
                float* m = &meta[0][t][0];
                m[0] = __int_as_float(s_);
                m[1] = sh.x * qdeg; m[2] = sh.y * qdeg; m[3] = sh.z * qdeg; m[4] = sh.w * qdeg;
                const float4* pe = (const float4*)(eemb + (size_t)eid * 8);
                *(float4*)(m + 8)  = pe[0];
                *(float4*)(m + 12) = pe[1];
            }
            __syncthreads();
            for (int i = t; i < 640; i += 256) {
                int e = i / 40, p = i - 40 * e;
                int src = __float_as_int(meta[0][e][0]);
                float4 val;
                int dsto;
                if (p < 16) { val = *(const float4*)(xs + (size_t)src * 64 + p * 4); dsto = p * 4; }
                else        { val = *(const float4*)(xv + (size_t)src * 96 + (p - 16) * 4); dsto = 64 + (p - 16) * 4; }
                *(float4*)&xsv[0][e][dsto] = val;
            }
        }

        int buf = 0;
        for (int i0 = 0; i0 < cnt; i0 += 16) {
            const bool more = (i0 + 16) < cnt;
            // A: meta for next batch into buf^1
            if (more && t < 16) {
                int i = i0 + 16 + t;
                bool valid = i < cnt;
                int eid = sorted[start + (valid ? i : 0)];
                int s_ = ei[eid];
                float4 sh = make_float4(0.f, 0.f, 0.f, 0.f);
                if (valid) sh = *(const float4*)(esh + (size_t)eid * 4);
                float* m = &meta[buf ^ 1][t][0];
                m[0] = __int_as_float(s_);
                m[1] = sh.x * qdeg; m[2] = sh.y * qdeg; m[3] = sh.z * qdeg; m[4] = sh.w * qdeg;
                const float4* pe = (const float4*)(eemb + (size_t)eid * 8);
                *(float4*)(m + 8)  = pe[0];
                *(float4*)(m + 12) = pe[1];
            }
            // B: layer-1 for current batch
            #pragma unroll
            for (int q = 0; q < 4; ++q) {
                int e = w * 4 + q;
                const float* m = &meta[buf][e][0];
                float a = b1r;
                a += m[8]  * w1r[0] + m[9]  * w1r[1] + m[10] * w1r[2] + m[11] * w1r[3];
                a += m[12] * w1r[4] + m[13] * w1r[5] + m[14] * w1r[6] + m[15] * w1r[7];
                float s = a / (1.f + __expf(-a));
                hid_lds[buf][e * 64 + (myh ^ ((e & 7) << 3))] = f2bf(s);
            }
            __syncthreads();   // hid[buf] + meta[buf^1] ready

            // C: stage next batch's xs/xv rows (latency overlapped with D/E)
            if (more) {
                for (int i = t; i < 640; i += 256) {
                    int e = i / 40, p = i - 40 * e;
                    int src = __float_as_int(meta[buf ^ 1][e][0]);
                    float4 val;
                    int dsto;
                    if (p < 16) { val = *(const float4*)(xs + (size_t)src * 64 + p * 4); dsto = p * 4; }
                    else        { val = *(const float4*)(xv + (size_t)src * 96 + (p - 16) * 4); dsto = 64 + (p - 16) * 4; }
                    *(float4*)&xsv[buf ^ 1][e][dsto] = val;
                }
            }

            // D: MFMA
            short8 a0 = *(const short8*)&hid_lds[buf][lr * 64 + ((lg * 8) ^ ((lr & 7) << 3))];
            short8 a1 = *(const short8*)&hid_lds[buf][lr * 64 + ((32 + lg * 8) ^ ((lr & 7) << 3))];

            f32x4 c0 = {0.f, 0.f, 0.f, 0.f}, c1 = c0, c2 = c0;
            c0 = __builtin_amdgcn_mfma_f32_16x16x32_bf16(a0, bfrag[0][0], c0, 0, 0, 0);
            c0 = __builtin_amdgcn_mfma_f32_16x16x32_bf16(a1, bfrag[0][1], c0, 0, 0, 0);
            c1 = __builtin_amdgcn_mfma_f32_16x16x32_bf16(a0, bfrag[1][0], c1, 0, 0, 0);
            c1 = __builtin_amdgcn_mfma_f32_16x16x32_bf16(a1, bfrag[1][1], c1, 0, 0, 0);
            c2 = __builtin_amdgcn_mfma_f32_16x16x32_bf16(a0, bfrag[2][0], c2, 0, 0, 0);
            c2 = __builtin_amdgcn_mfma_f32_16x16x32_bf16(a1, bfrag[2][1], c2, 0, 0, 0);

            // E: combine from LDS-staged xs/xv. C row (lg*4+r) = edge slot, col = lr
            #pragma unroll
            for (int r = 0; r < 4; ++r) {
                int er = lg * 4 + r;
                const float* m = &meta[buf][er][0];
                float sh0 = m[1], s1x = m[2], s1y = m[3], s1z = m[4];
                const float* xr = &xsv[buf][er][0];
                #pragma unroll
                for (int tt = 0; tt < 3; ++tt) {
                    float val = (tt == 0) ? c0[r] : ((tt == 1) ? c1[r] : c2[r]);
                    int rtt = w * 3 + tt;
                    if (rtt < 4) {                      // m0_a
                        int j = rtt * 16 + lr;
                        acc[tt][0] += val * xr[j] * sh0;
                    } else if (rtt < 8) {               // m1_a
                        int j = (rtt - 4) * 16 + lr;
                        float tmp = val * xr[j];
                        acc[tt][0] += tmp * s1x; acc[tt][1] += tmp * s1y; acc[tt][2] += tmp * s1z;
                    } else if (rtt < 10) {              // m1_b
                        int k = (rtt - 8) * 16 + lr;
                        float v0 = xr[64 + 3 * k], v1 = xr[64 + 3 * k + 1], v2 = xr[64 + 3 * k + 2];
                        float tmp = val * sh0;
                        acc[tt][0] += tmp * v0; acc[tt][1] += tmp * v1; acc[tt][2] += tmp * v2;
                    } else {                            // m0_b
                        int k = (rtt - 10) * 16 + lr;
                        float v0 = xr[64 + 3 * k], v1 = xr[64 + 3 * k + 1], v2 = xr[64 + 3 * k + 2];
                        float dv = v0 * s1x + v1 * s1y + v2 * s1z;
                        acc[tt][0] += val * dv * inv_s3;
                    }
                }
            }
            __syncthreads();   // protect meta[buf]/xsv[buf] from next iter overwrite
            buf ^= 1;
        }

        float* row = agg + (size_t)node * 384;
        #pragma unroll
        for (int tt = 0; tt < 3; ++tt) {
            int rtt = w * 3 + tt;
            if (rtt < 4) {
                float v = acc[tt][0]; v += __shfl_xor(v, 16); v += __shfl_xor(v, 32);
                if (l < 16) row[rtt * 16 + l] = v;
            } else if (rtt < 8) {
                float vx = acc[tt][0]; vx += __shfl_xor(vx, 16); vx += __shfl_xor(vx, 32);
                float vy = acc[tt][1]; vy += __shfl_xor(vy, 16); vy += __shfl_xor(vy, 32);
                float vz = acc[tt][2]; vz += __shfl_xor(vz, 16); vz += __shfl_xor(vz, 32);
                if (l < 16) {
                    int j = (rtt - 4) * 16 + l;
                    row[96 + 3 * j] = vx; row[96 + 3 * j + 1] = vy; row[96 + 3 * j + 2] = vz;
                }
            } else if (rtt < 10) {
                float vx = acc[tt][0]; vx += __shfl_xor(vx, 16); vx += __shfl_xor(vx, 32);
                float vy = acc[tt][1]; vy += __shfl_xor(vy, 16); vy += __shfl_xor(vy, 32);
                float vz = acc[tt][2]; vz += __shfl_xor(vz, 16); vz += __shfl_xor(vz, 32);
                if (l < 16) {
                    int k = (rtt - 8) * 16 + l;
                    row[288 + 3 * k] = vx; row[288 + 3 * k + 1] = vy; row[288 + 3 * k + 2] = vz;
                }
            } else {
                float v = acc[tt][0]; v += __shfl_xor(v, 16); v += __shfl_xor(v, 32);
                if (l < 16) row[64 + (rtt - 10) * 16 + l] = v;
            }
        }
    }
}

// ---------------- node post: linear + gating + residual ----------------
__global__ __launch_bounds__(256) void k_node_post(
    const float* __restrict__ nf, const float* __restrict__ agg,
    const float* __restrict__ W2s, const float* __restrict__ W2v,
    const float* __restrict__ Wscs, const float* __restrict__ Wscv,
    float* __restrict__ out, int n)
{
    __shared__ float ag[2][384];
    __shared__ float sv[2][160];
    __shared__ float gsrc[2][32];
    int half = threadIdx.x >> 7;
    int t = threadIdx.x & 127;
    int node = blockIdx.x * 2 + half;
    if (node < n) {
        for (int i = t; i < 384; i += 128) ag[half][i] = agg[(long)node * 384 + i];
        for (int i = t; i < 160; i += 128) sv[half][i] = nf[(long)node * 160 + i];
    }
    __syncthreads();
    if (node >= n) return;

    const float c96 = 0.10206207261596577f;  // 1/sqrt(96)
    float osv = 0.f, ovv = 0.f;
    int k = t & 31, c = t >> 5;
    if (t < 96) {
        float a = 0.f;
        #pragma unroll 4
        for (int i = 0; i < 96; ++i) a += ag[half][i] * W2s[i * 96 + t];
        float b = 0.f;
        #pragma unroll 4
        for (int i = 0; i < 64; ++i) b += sv[half][i] * Wscs[i * 96 + t];
        osv = a * c96 + b * 0.125f;
        float av = 0.f;
        #pragma unroll 4
        for (int m = 0; m < 96; ++m) av += ag[half][96 + 3 * m + c] * W2v[m * 32 + k];
        float bv = 0.f;
        #pragma unroll 4
        for (int m = 0; m < 32; ++m) bv += sv[half][64 + 3 * m + c] * Wscv[m * 32 + k];
        ovv = av * c96 + bv * 0.17677669529663687f;
        if (t >= 64) gsrc[half][t - 64] = osv;
    }
    __syncthreads();
    if (t < 64) out[(long)node * 160 + t] = sv[half][t] + silu_f(osv);
    if (t < 96) {
        float g = silu_f(gsrc[half][k]);
        out[(long)node * 160 + 64 + 3 * k + c] = sv[half][64 + 3 * k + c] + ovv * g;
    }
}

extern "C" void kernel_launch(void* const* d_in, const int* in_sizes, int n_in,
                              void* d_out, int out_size, void* d_ws, size_t ws_size,
                              hipStream_t stream)
{
    const float* nf   = (const float*)d_in[0];
    const float* esh  = (const float*)d_in[1];
    const float* eemb = (const float*)d_in[2];
    const float* W1s  = (const float*)d_in[3];
    const float* W1v  = (const float*)d_in[4];
    const float* fcw1 = (const float*)d_in[5];
    const float* fcb1 = (const float*)d_in[6];
    const float* fcw2 = (const float*)d_in[7];
    const float* fcb2 = (const float*)d_in[8];
    const float* W2s  = (const float*)d_in[9];
    const float* W2v  = (const float*)d_in[10];
    const float* Wscs = (const float*)d_in[11];
    const float* Wscv = (const float*)d_in[12];
    const int*   ei   = (const int*)d_in[13];
    float* out = (float*)d_out;

    int nN = in_sizes[0] / 160;
    int nE = in_sizes[13] / 2;

    // ws layout identical to round 3 (proven): ~112.8 MB
    float* xs   = (float*)d_ws;
    float* xv   = xs + (size_t)nN * 64;
    float* agg  = xv + (size_t)nN * 96;
    int* deg    = (int*)(agg + (size_t)nN * 384);
    int* offs   = deg + nN;
    int* cursor = offs + nN;
    int* incl   = cursor + nN;
    int* sorted = incl + nN;
    int* partials = sorted + nE;

    int nb1 = (nN + 1023) / 1024;

    hipMemsetAsync(deg, 0, (size_t)nN * sizeof(int), stream);
    k_node_pre<<<(nN + 3) / 4, 256, 0, stream>>>(nf, W1s, W1v, xs, xv, nN);
    k_hist<<<(nE + 255) / 256, 256, 0, stream>>>(ei, deg, nE);
    k_scan1<<<nb1, 256, 0, stream>>>(deg, incl, partials, nN);
    k_scan2<<<1, 64, 0, stream>>>(partials, nb1);
    k_scan3<<<(nN + 255) / 256, 256, 0, stream>>>(incl, deg, partials, offs, cursor, nN);
    k_scatter<<<(nE + 255) / 256, 256, 0, stream>>>(ei, cursor, sorted, nE);
    k_gather_mfma<<<2048, 256, 0, stream>>>(esh, eemb, fcw1, fcb1, fcw2, fcb2, ei,
                                            xs, xv, offs, deg, sorted, agg, nN);
    k_node_post<<<(nN + 1) / 2, 256, 0, stream>>>(nf, agg, W2s, W2v, Wscs, Wscv, out, nN);
}